// Round 1
// baseline (696.732 us; speedup 1.0000x reference)
//
#include <hip/hip_runtime.h>

#define N_NODES 50000
#define N_EDGES 800000
#define DIM 64

// ---- monotone float<->uint mapping so unsigned atomicMax == float max ----
__device__ __forceinline__ unsigned f2mono(float x) {
    unsigned b = __float_as_uint(x);
    return (b & 0x80000000u) ? ~b : (b | 0x80000000u);
}
__device__ __forceinline__ float mono2f(unsigned u) {
    unsigned b = (u & 0x80000000u) ? (u & 0x7FFFFFFFu) : ~u;
    return __uint_as_float(b);
}

// z = h @ W^T, zi = h @ U^T, s_src[n] = z[n]. A[0:64], s_dst[n] = z[n] . A[64:128]
// 64 rows per block, 256 threads, each thread computes 4x4 outputs for both matrices.
__global__ __launch_bounds__(256) void node_linear(
    const float* __restrict__ h, const float* __restrict__ W,
    const float* __restrict__ U, const float* __restrict__ A,
    float* __restrict__ z, float* __restrict__ zi,
    float* __restrict__ s_src, float* __restrict__ s_dst)
{
    __shared__ float Ws[DIM][DIM + 1];
    __shared__ float Us[DIM][DIM + 1];
    __shared__ float hs[64][DIM + 1];

    const int tid = threadIdx.x;
    const int row0 = blockIdx.x * 64;

    for (int i = tid; i < DIM * DIM; i += 256) {
        int r = i >> 6, c = i & 63;
        Ws[r][c] = W[i];
        Us[r][c] = U[i];
    }
    for (int i = tid; i < 64 * DIM; i += 256) {
        int r = i >> 6, c = i & 63;
        int n = row0 + r;
        hs[r][c] = (n < N_NODES) ? h[(size_t)n * DIM + c] : 0.f;
    }
    __syncthreads();

    const int rb = (tid >> 4) * 4;   // row base within the 64-row tile
    const int cb = (tid & 15) * 4;   // col base

    float accz[4][4] = {{0}}, accu[4][4] = {{0}};
    #pragma unroll 8
    for (int k = 0; k < DIM; ++k) {
        float hv[4], wv[4], uv[4];
        #pragma unroll
        for (int r = 0; r < 4; ++r) hv[r] = hs[rb + r][k];
        #pragma unroll
        for (int c = 0; c < 4; ++c) { wv[c] = Ws[cb + c][k]; uv[c] = Us[cb + c][k]; }
        #pragma unroll
        for (int r = 0; r < 4; ++r)
            #pragma unroll
            for (int c = 0; c < 4; ++c) {
                accz[r][c] += hv[r] * wv[c];
                accu[r][c] += hv[r] * uv[c];
            }
    }

    // store z, zi (float4 per row-chunk) and reduce attention projections
    float asrc[4], adst[4];
    #pragma unroll
    for (int c = 0; c < 4; ++c) { asrc[c] = A[cb + c]; adst[c] = A[DIM + cb + c]; }

    float ps[4], pd[4];
    #pragma unroll
    for (int r = 0; r < 4; ++r) {
        int n = row0 + rb + r;
        if (n < N_NODES) {
            float4 vz = make_float4(accz[r][0], accz[r][1], accz[r][2], accz[r][3]);
            float4 vu = make_float4(accu[r][0], accu[r][1], accu[r][2], accu[r][3]);
            *(float4*)&z[(size_t)n * DIM + cb]  = vz;
            *(float4*)&zi[(size_t)n * DIM + cb] = vu;
        }
        float s = 0.f, t = 0.f;
        #pragma unroll
        for (int c = 0; c < 4; ++c) { s += accz[r][c] * asrc[c]; t += accz[r][c] * adst[c]; }
        ps[r] = s; pd[r] = t;
    }
    // reduce across the 16 lanes that share this row group (lanes differ in cb)
    #pragma unroll
    for (int m = 1; m < 16; m <<= 1) {
        #pragma unroll
        for (int r = 0; r < 4; ++r) {
            ps[r] += __shfl_xor(ps[r], m, 64);
            pd[r] += __shfl_xor(pd[r], m, 64);
        }
    }
    if ((tid & 15) == 0) {
        #pragma unroll
        for (int r = 0; r < 4; ++r) {
            int n = row0 + rb + r;
            if (n < N_NODES) { s_src[n] = ps[r]; s_dst[n] = pd[r]; }
        }
    }
}

__global__ __launch_bounds__(256) void init_m(unsigned* __restrict__ mu)
{
    int i = blockIdx.x * 256 + threadIdx.x;
    if (i < N_NODES) mu[i] = 0x007FFFFFu;  // f2mono(-inf)
}

// e = leaky_relu(s_src[src] + s_dst[dst] + d*V*a_e); store e; segment max into mu[dst]
__global__ __launch_bounds__(256) void edge_logit(
    const float* __restrict__ dfeat, const int* __restrict__ src, const int* __restrict__ dst,
    const float* __restrict__ V, const float* __restrict__ A,
    const float* __restrict__ s_src, const float* __restrict__ s_dst,
    float* __restrict__ e_ws, unsigned* __restrict__ mu)
{
    int e = blockIdx.x * 256 + threadIdx.x;
    if (e >= N_EDGES) return;
    int s = src[e], t = dst[e];
    float vae = V[0] * A[2 * DIM];
    float val = s_src[s] + s_dst[t] + dfeat[e] * vae;
    val = (val >= 0.f) ? val : 0.01f * val;
    e_ws[e] = val;
    atomicMax(&mu[t], f2mono(val));
}

// ex = exp(e - m[dst]); store ex; segment sum into denom[dst]
__global__ __launch_bounds__(256) void edge_exp(
    const int* __restrict__ dst, float* __restrict__ e_ws,
    const unsigned* __restrict__ mu, float* __restrict__ denom)
{
    int e = blockIdx.x * 256 + threadIdx.x;
    if (e >= N_EDGES) return;
    int t = dst[e];
    float ex = __expf(e_ws[e] - mono2f(mu[t]));
    e_ws[e] = ex;
    unsafeAtomicAdd(&denom[t], ex);
}

// agg[dst] += (ex/denom[dst]) * z[src]   -- one wave per edge, lane = dim
__global__ __launch_bounds__(256) void edge_agg(
    const int* __restrict__ src, const int* __restrict__ dst,
    const float* __restrict__ e_ws, const float* __restrict__ denom,
    const float* __restrict__ z, float* __restrict__ agg)
{
    int e = blockIdx.x * 4 + (threadIdx.x >> 6);
    int j = threadIdx.x & 63;
    if (e >= N_EDGES) return;
    int s = src[e], t = dst[e];
    float alpha = e_ws[e] / denom[t];
    float v = alpha * z[(size_t)s * DIM + j];
    unsafeAtomicAdd(&agg[(size_t)t * DIM + j], v);
}

// out = deg>0 ? relu(zi + agg) : 0   (deg>0 <=> denom>0)
__global__ __launch_bounds__(256) void node_out(
    const float* __restrict__ zi, const float* __restrict__ agg,
    const float* __restrict__ denom, float* __restrict__ out)
{
    int i = blockIdx.x * 256 + threadIdx.x;
    if (i >= N_NODES * DIM) return;
    int n = i >> 6;
    float v = (denom[n] > 0.f) ? fmaxf(zi[i] + agg[i], 0.f) : 0.f;
    out[i] = v;
}

static void run_layer(const float* h, const float* dfeat, const int* src, const int* dst,
                      const float* V, const float* W, const float* U, const float* A,
                      float* z, float* zi, float* ssrc, float* sdst,
                      unsigned* mu, float* e_ws, float* denom, float* agg,
                      float* out, hipStream_t stream)
{
    const size_t ND = (size_t)N_NODES * DIM;
    node_linear<<<(N_NODES + 63) / 64, 256, 0, stream>>>(h, W, U, A, z, zi, ssrc, sdst);
    init_m<<<(N_NODES + 255) / 256, 256, 0, stream>>>(mu);
    // denom and agg are laid out contiguously -> one async memset
    hipMemsetAsync(denom, 0, (N_NODES + ND) * sizeof(float), stream);
    edge_logit<<<(N_EDGES + 255) / 256, 256, 0, stream>>>(dfeat, src, dst, V, A, ssrc, sdst, e_ws, mu);
    edge_exp<<<(N_EDGES + 255) / 256, 256, 0, stream>>>(dst, e_ws, mu, denom);
    edge_agg<<<(N_EDGES + 3) / 4, 256, 0, stream>>>(src, dst, e_ws, denom, z, agg);
    node_out<<<((int)ND + 255) / 256, 256, 0, stream>>>(zi, agg, denom, out);
}

extern "C" void kernel_launch(void* const* d_in, const int* in_sizes, int n_in,
                              void* d_out, int out_size, void* d_ws, size_t ws_size,
                              hipStream_t stream)
{
    const float* h  = (const float*)d_in[0];
    const float* dd = (const float*)d_in[1];
    const int* src  = (const int*)d_in[2];
    const int* dst  = (const int*)d_in[3];
    const float* V0 = (const float*)d_in[4];
    const float* W0 = (const float*)d_in[5];
    const float* U0 = (const float*)d_in[6];
    const float* A0 = (const float*)d_in[7];
    const float* V1 = (const float*)d_in[8];
    const float* W1 = (const float*)d_in[9];
    const float* U1 = (const float*)d_in[10];
    const float* A1 = (const float*)d_in[11];

    const size_t ND = (size_t)N_NODES * DIM;
    float* ws    = (float*)d_ws;
    float* z     = ws;                 // ND
    float* zi    = z + ND;             // ND
    float* ssrc  = zi + ND;            // N
    float* sdst  = ssrc + N_NODES;     // N
    unsigned* mu = (unsigned*)(sdst + N_NODES);  // N
    float* e_ws  = (float*)(mu + N_NODES);       // E
    float* denom = e_ws + N_EDGES;     // N   (contiguous with agg for one memset)
    float* agg   = denom + N_NODES;    // ND
    float* h1    = agg + ND;           // ND
    float* out   = (float*)d_out;

    run_layer(h,  dd, src, dst, V0, W0, U0, A0, z, zi, ssrc, sdst, mu, e_ws, denom, agg, h1,  stream);
    run_layer(h1, dd, src, dst, V1, W1, U1, A1, z, zi, ssrc, sdst, mu, e_ws, denom, agg, out, stream);
}

// Round 2
// 366.682 us; speedup vs baseline: 1.9001x; 1.9001x over previous
//
#include <hip/hip_runtime.h>
#include <math.h>

#define N_NODES 50000
#define N_EDGES 800000
#define DIM 64
#define NB_SCAN ((N_NODES + 255) / 256)

// ============================== node GEMM ==============================
// z = h @ W^T, zi = h @ U^T, s_src[n] = z[n].A[0:64], s_dst[n] = z[n].A[64:128]
__global__ __launch_bounds__(256) void node_linear(
    const float* __restrict__ h, const float* __restrict__ W,
    const float* __restrict__ U, const float* __restrict__ A,
    float* __restrict__ z, float* __restrict__ zi,
    float* __restrict__ s_src, float* __restrict__ s_dst)
{
    __shared__ float Ws[DIM][DIM + 1];
    __shared__ float Us[DIM][DIM + 1];
    __shared__ float hs[64][DIM + 1];

    const int tid = threadIdx.x;
    const int row0 = blockIdx.x * 64;

    for (int i = tid; i < DIM * DIM; i += 256) {
        int r = i >> 6, c = i & 63;
        Ws[r][c] = W[i];
        Us[r][c] = U[i];
    }
    for (int i = tid; i < 64 * DIM; i += 256) {
        int r = i >> 6, c = i & 63;
        int n = row0 + r;
        hs[r][c] = (n < N_NODES) ? h[(size_t)n * DIM + c] : 0.f;
    }
    __syncthreads();

    const int rb = (tid >> 4) * 4;
    const int cb = (tid & 15) * 4;

    float accz[4][4] = {{0}}, accu[4][4] = {{0}};
    #pragma unroll 8
    for (int k = 0; k < DIM; ++k) {
        float hv[4], wv[4], uv[4];
        #pragma unroll
        for (int r = 0; r < 4; ++r) hv[r] = hs[rb + r][k];
        #pragma unroll
        for (int c = 0; c < 4; ++c) { wv[c] = Ws[cb + c][k]; uv[c] = Us[cb + c][k]; }
        #pragma unroll
        for (int r = 0; r < 4; ++r)
            #pragma unroll
            for (int c = 0; c < 4; ++c) {
                accz[r][c] += hv[r] * wv[c];
                accu[r][c] += hv[r] * uv[c];
            }
    }

    float asrc[4], adst[4];
    #pragma unroll
    for (int c = 0; c < 4; ++c) { asrc[c] = A[cb + c]; adst[c] = A[DIM + cb + c]; }

    float ps[4], pd[4];
    #pragma unroll
    for (int r = 0; r < 4; ++r) {
        int n = row0 + rb + r;
        if (n < N_NODES) {
            float4 vz = make_float4(accz[r][0], accz[r][1], accz[r][2], accz[r][3]);
            float4 vu = make_float4(accu[r][0], accu[r][1], accu[r][2], accu[r][3]);
            *(float4*)&z[(size_t)n * DIM + cb]  = vz;
            *(float4*)&zi[(size_t)n * DIM + cb] = vu;
        }
        float s = 0.f, t = 0.f;
        #pragma unroll
        for (int c = 0; c < 4; ++c) { s += accz[r][c] * asrc[c]; t += accz[r][c] * adst[c]; }
        ps[r] = s; pd[r] = t;
    }
    #pragma unroll
    for (int m = 1; m < 16; m <<= 1) {
        #pragma unroll
        for (int r = 0; r < 4; ++r) {
            ps[r] += __shfl_xor(ps[r], m, 64);
            pd[r] += __shfl_xor(pd[r], m, 64);
        }
    }
    if ((tid & 15) == 0) {
        #pragma unroll
        for (int r = 0; r < 4; ++r) {
            int n = row0 + rb + r;
            if (n < N_NODES) { s_src[n] = ps[r]; s_dst[n] = pd[r]; }
        }
    }
}

// ============================== CSR build ==============================
__global__ __launch_bounds__(256) void hist_kernel(const int* __restrict__ dst, int* __restrict__ counts)
{
    int e = blockIdx.x * 256 + threadIdx.x;
    if (e < N_EDGES) atomicAdd(&counts[dst[e]], 1);
}

// per-block exclusive scan; block sums to partials
__global__ __launch_bounds__(256) void scan_blocks(const int* __restrict__ counts,
                                                   int* __restrict__ excl, int* __restrict__ partials)
{
    __shared__ int tmp[256];
    int i = blockIdx.x * 256 + threadIdx.x;
    int v = (i < N_NODES) ? counts[i] : 0;
    tmp[threadIdx.x] = v;
    __syncthreads();
    for (int off = 1; off < 256; off <<= 1) {
        int t = (threadIdx.x >= off) ? tmp[threadIdx.x - off] : 0;
        __syncthreads();
        tmp[threadIdx.x] += t;
        __syncthreads();
    }
    if (i < N_NODES) excl[i] = tmp[threadIdx.x] - v;
    if (threadIdx.x == 255) partials[blockIdx.x] = tmp[255];
}

__global__ __launch_bounds__(256) void scan_partials(int* __restrict__ partials)
{
    __shared__ int tmp[256];
    int v = (threadIdx.x < NB_SCAN) ? partials[threadIdx.x] : 0;
    tmp[threadIdx.x] = v;
    __syncthreads();
    for (int off = 1; off < 256; off <<= 1) {
        int t = (threadIdx.x >= off) ? tmp[threadIdx.x - off] : 0;
        __syncthreads();
        tmp[threadIdx.x] += t;
        __syncthreads();
    }
    if (threadIdx.x < NB_SCAN) partials[threadIdx.x] = tmp[threadIdx.x] - v;
}

__global__ __launch_bounds__(256) void scan_add(const int* __restrict__ excl, const int* __restrict__ partials,
                                                int* __restrict__ rowptr, int* __restrict__ cursor)
{
    int i = blockIdx.x * 256 + threadIdx.x;
    if (i < N_NODES) {
        int v = excl[i] + partials[blockIdx.x];
        rowptr[i] = v;
        cursor[i] = v;
    }
    if (i == 0) rowptr[N_NODES] = N_EDGES;
}

__global__ __launch_bounds__(256) void scatter_kernel(
    const int* __restrict__ src, const int* __restrict__ dst, const float* __restrict__ dfeat,
    int* __restrict__ cursor, int* __restrict__ srcs, float* __restrict__ dvals)
{
    int e = blockIdx.x * 256 + threadIdx.x;
    if (e >= N_EDGES) return;
    int t = dst[e];
    int pos = atomicAdd(&cursor[t], 1);
    srcs[pos] = src[e];
    dvals[pos] = dfeat[e];
}

// ============================== fused GAT ==============================
// one wave per dst node: logits -> online softmax -> weighted z-gather -> relu(zi+agg)
__global__ __launch_bounds__(256) void gat_fused(
    const int* __restrict__ rowptr, const int* __restrict__ srcs, const float* __restrict__ dvals,
    const float* __restrict__ s_src, const float* __restrict__ s_dst,
    const float* __restrict__ z, const float* __restrict__ zi,
    const float* __restrict__ V, const float* __restrict__ A,
    float* __restrict__ out)
{
    int n = blockIdx.x * 4 + (threadIdx.x >> 6);
    int lane = threadIdx.x & 63;
    if (n >= N_NODES) return;

    int beg = rowptr[n], end = rowptr[n + 1];
    size_t obase = (size_t)n * DIM;
    if (beg == end) { out[obase + lane] = 0.f; return; }

    float vae = V[0] * A[2 * DIM];
    float sd = s_dst[n];

    float m = -INFINITY, l = 0.f, acc = 0.f;
    for (int c0 = beg; c0 < end; c0 += 64) {
        int c = c0 + lane;
        bool valid = c < end;
        int s = valid ? srcs[c] : 0;
        float e = valid ? (s_src[s] + sd + dvals[c] * vae) : -INFINITY;
        e = (e >= 0.f) ? e : 0.01f * e;

        float cm = e;
        #pragma unroll
        for (int off = 32; off >= 1; off >>= 1) cm = fmaxf(cm, __shfl_xor(cm, off, 64));
        float nm = fmaxf(m, cm);

        float ex = valid ? __expf(e - nm) : 0.f;
        float cs = ex;
        #pragma unroll
        for (int off = 32; off >= 1; off >>= 1) cs += __shfl_xor(cs, off, 64);

        float scale = (m == -INFINITY) ? 0.f : __expf(m - nm);
        l = l * scale + cs;
        acc *= scale;

        int cnt = min(64, end - c0);
        for (int k = 0; k < cnt; ++k) {
            float exk = __shfl(ex, k, 64);
            int sk   = __shfl(s, k, 64);
            acc += exk * z[(size_t)sk * DIM + lane];
        }
        m = nm;
    }
    float v = zi[obase + lane] + acc / l;
    out[obase + lane] = fmaxf(v, 0.f);
}

// ============================== driver ==============================
static void run_layer(const float* h, const float* V, const float* W, const float* U, const float* A,
                      const int* rowptr, const int* srcs, const float* dvals,
                      float* z, float* zi, float* ssrc, float* sdst,
                      float* out, hipStream_t stream)
{
    node_linear<<<(N_NODES + 63) / 64, 256, 0, stream>>>(h, W, U, A, z, zi, ssrc, sdst);
    gat_fused<<<(N_NODES + 3) / 4, 256, 0, stream>>>(rowptr, srcs, dvals, ssrc, sdst, z, zi, V, A, out);
}

extern "C" void kernel_launch(void* const* d_in, const int* in_sizes, int n_in,
                              void* d_out, int out_size, void* d_ws, size_t ws_size,
                              hipStream_t stream)
{
    const float* h  = (const float*)d_in[0];
    const float* dd = (const float*)d_in[1];
    const int* src  = (const int*)d_in[2];
    const int* dst  = (const int*)d_in[3];
    const float* V0 = (const float*)d_in[4];
    const float* W0 = (const float*)d_in[5];
    const float* U0 = (const float*)d_in[6];
    const float* A0 = (const float*)d_in[7];
    const float* V1 = (const float*)d_in[8];
    const float* W1 = (const float*)d_in[9];
    const float* U1 = (const float*)d_in[10];
    const float* A1 = (const float*)d_in[11];

    const size_t ND = (size_t)N_NODES * DIM;
    float* ws     = (float*)d_ws;
    float* z      = ws;                    // ND
    float* zi     = z + ND;                // ND
    float* h1     = zi + ND;               // ND
    float* ssrc   = h1 + ND;               // N
    float* sdst   = ssrc + N_NODES;        // N
    float* dvals  = sdst + N_NODES;        // E
    int*   srcs   = (int*)(dvals + N_EDGES);       // E
    int*   counts = srcs + N_EDGES;        // N
    int*   excl   = counts + N_NODES;      // N
    int*   rowptr = excl + N_NODES;        // N+1
    int*   cursor = rowptr + N_NODES + 1;  // N
    int*   partials = cursor + N_NODES;    // 256
    float* out    = (float*)d_out;

    // ---- CSR build (once; shared by both layers) ----
    hipMemsetAsync(counts, 0, N_NODES * sizeof(int), stream);
    hist_kernel<<<(N_EDGES + 255) / 256, 256, 0, stream>>>(dst, counts);
    scan_blocks<<<NB_SCAN, 256, 0, stream>>>(counts, excl, partials);
    scan_partials<<<1, 256, 0, stream>>>(partials);
    scan_add<<<NB_SCAN, 256, 0, stream>>>(excl, partials, rowptr, cursor);
    scatter_kernel<<<(N_EDGES + 255) / 256, 256, 0, stream>>>(src, dst, dd, cursor, srcs, dvals);

    // ---- two GAT layers ----
    run_layer(h,  V0, W0, U0, A0, rowptr, srcs, dvals, z, zi, ssrc, sdst, h1,  stream);
    run_layer(h1, V1, W1, U1, A1, rowptr, srcs, dvals, z, zi, ssrc, sdst, out, stream);
}

// Round 3
// 295.704 us; speedup vs baseline: 2.3562x; 1.2400x over previous
//
#include <hip/hip_runtime.h>
#include <math.h>

#define N_NODES 50000
#define N_EDGES 800000
#define DIM 64
#define NB_SCAN ((N_NODES + 255) / 256)

// ---- bf16 helpers (RNE) ----
__device__ __forceinline__ ushort f2bf(float x) {
    unsigned b = __float_as_uint(x);
    return (ushort)((b + 0x7FFFu + ((b >> 16) & 1u)) >> 16);
}
__device__ __forceinline__ float bf2f(ushort u) {
    return __uint_as_float(((unsigned)u) << 16);
}

// ============================== node GEMM ==============================
// zb = bf16(h @ W^T), zi = h @ U^T, s_src[n] = z[n].A[0:64], s_dst[n] = z[n].A[64:128]
__global__ __launch_bounds__(256) void node_linear(
    const float* __restrict__ h, const float* __restrict__ W,
    const float* __restrict__ U, const float* __restrict__ A,
    ushort* __restrict__ zb, float* __restrict__ zi,
    float* __restrict__ s_src, float* __restrict__ s_dst)
{
    __shared__ float Ws[DIM][DIM + 1];
    __shared__ float Us[DIM][DIM + 1];
    __shared__ float hs[64][DIM + 1];

    const int tid = threadIdx.x;
    const int row0 = blockIdx.x * 64;

    // vectorized staging: 1024 float4 per 64x64 tile
    for (int i = tid; i < 1024; i += 256) {
        int r = i >> 4, c = (i & 15) * 4;
        float4 w4 = ((const float4*)W)[i];
        float4 u4 = ((const float4*)U)[i];
        Ws[r][c] = w4.x; Ws[r][c + 1] = w4.y; Ws[r][c + 2] = w4.z; Ws[r][c + 3] = w4.w;
        Us[r][c] = u4.x; Us[r][c + 1] = u4.y; Us[r][c + 2] = u4.z; Us[r][c + 3] = u4.w;
        int n = row0 + r;
        float4 h4 = (n < N_NODES) ? ((const float4*)h)[((size_t)n * DIM + c) >> 2]
                                  : make_float4(0.f, 0.f, 0.f, 0.f);
        hs[r][c] = h4.x; hs[r][c + 1] = h4.y; hs[r][c + 2] = h4.z; hs[r][c + 3] = h4.w;
    }
    __syncthreads();

    const int rb = (tid >> 4) * 4;
    const int cb = (tid & 15) * 4;

    float accz[4][4] = {{0}}, accu[4][4] = {{0}};
    #pragma unroll 8
    for (int k = 0; k < DIM; ++k) {
        float hv[4], wv[4], uv[4];
        #pragma unroll
        for (int r = 0; r < 4; ++r) hv[r] = hs[rb + r][k];
        #pragma unroll
        for (int c = 0; c < 4; ++c) { wv[c] = Ws[cb + c][k]; uv[c] = Us[cb + c][k]; }
        #pragma unroll
        for (int r = 0; r < 4; ++r)
            #pragma unroll
            for (int c = 0; c < 4; ++c) {
                accz[r][c] += hv[r] * wv[c];
                accu[r][c] += hv[r] * uv[c];
            }
    }

    float asrc[4], adst[4];
    #pragma unroll
    for (int c = 0; c < 4; ++c) { asrc[c] = A[cb + c]; adst[c] = A[DIM + cb + c]; }

    float ps[4], pd[4];
    #pragma unroll
    for (int r = 0; r < 4; ++r) {
        int n = row0 + rb + r;
        if (n < N_NODES) {
            ushort4 vz;
            vz.x = f2bf(accz[r][0]); vz.y = f2bf(accz[r][1]);
            vz.z = f2bf(accz[r][2]); vz.w = f2bf(accz[r][3]);
            *(ushort4*)&zb[(size_t)n * DIM + cb] = vz;
            float4 vu = make_float4(accu[r][0], accu[r][1], accu[r][2], accu[r][3]);
            *(float4*)&zi[(size_t)n * DIM + cb] = vu;
        }
        float s = 0.f, t = 0.f;
        #pragma unroll
        for (int c = 0; c < 4; ++c) { s += accz[r][c] * asrc[c]; t += accz[r][c] * adst[c]; }
        ps[r] = s; pd[r] = t;
    }
    #pragma unroll
    for (int m = 1; m < 16; m <<= 1) {
        #pragma unroll
        for (int r = 0; r < 4; ++r) {
            ps[r] += __shfl_xor(ps[r], m, 64);
            pd[r] += __shfl_xor(pd[r], m, 64);
        }
    }
    if ((tid & 15) == 0) {
        #pragma unroll
        for (int r = 0; r < 4; ++r) {
            int n = row0 + rb + r;
            if (n < N_NODES) { s_src[n] = ps[r]; s_dst[n] = pd[r]; }
        }
    }
}

// ============================== CSR build ==============================
__global__ __launch_bounds__(256) void hist_kernel(const int* __restrict__ dst, int* __restrict__ counts)
{
    int e = blockIdx.x * 256 + threadIdx.x;
    if (e < N_EDGES) atomicAdd(&counts[dst[e]], 1);
}

__global__ __launch_bounds__(256) void scan_blocks(const int* __restrict__ counts,
                                                   int* __restrict__ excl, int* __restrict__ partials)
{
    __shared__ int tmp[256];
    int i = blockIdx.x * 256 + threadIdx.x;
    int v = (i < N_NODES) ? counts[i] : 0;
    tmp[threadIdx.x] = v;
    __syncthreads();
    for (int off = 1; off < 256; off <<= 1) {
        int t = (threadIdx.x >= off) ? tmp[threadIdx.x - off] : 0;
        __syncthreads();
        tmp[threadIdx.x] += t;
        __syncthreads();
    }
    if (i < N_NODES) excl[i] = tmp[threadIdx.x] - v;
    if (threadIdx.x == 255) partials[blockIdx.x] = tmp[255];
}

__global__ __launch_bounds__(256) void scan_partials(int* __restrict__ partials)
{
    __shared__ int tmp[256];
    int v = (threadIdx.x < NB_SCAN) ? partials[threadIdx.x] : 0;
    tmp[threadIdx.x] = v;
    __syncthreads();
    for (int off = 1; off < 256; off <<= 1) {
        int t = (threadIdx.x >= off) ? tmp[threadIdx.x - off] : 0;
        __syncthreads();
        tmp[threadIdx.x] += t;
        __syncthreads();
    }
    if (threadIdx.x < NB_SCAN) partials[threadIdx.x] = tmp[threadIdx.x] - v;
}

__global__ __launch_bounds__(256) void scan_add(const int* __restrict__ excl, const int* __restrict__ partials,
                                                int* __restrict__ rowptr, int* __restrict__ cursor)
{
    int i = blockIdx.x * 256 + threadIdx.x;
    if (i < N_NODES) {
        int v = excl[i] + partials[blockIdx.x];
        rowptr[i] = v;
        cursor[i] = v;
    }
    if (i == 0) rowptr[N_NODES] = N_EDGES;
}

__global__ __launch_bounds__(256) void scatter_kernel(
    const int* __restrict__ src, const int* __restrict__ dst, const float* __restrict__ dfeat,
    int* __restrict__ cursor, int2* __restrict__ edata)
{
    int e = blockIdx.x * 256 + threadIdx.x;
    if (e >= N_EDGES) return;
    int t = dst[e];
    int pos = atomicAdd(&cursor[t], 1);
    edata[pos] = make_int2(src[e], __float_as_int(dfeat[e]));
}

// ============================== fused GAT ==============================
// one wave per dst node: logits -> softmax (no max-shift; logits are O(1)) ->
// weighted bf16 z-gather with 4-way ILP -> relu(zi + agg/l)
__global__ __launch_bounds__(256) void gat_fused(
    const int* __restrict__ rowptr, const int2* __restrict__ edata,
    const float* __restrict__ s_src, const float* __restrict__ s_dst,
    const ushort* __restrict__ zb, const float* __restrict__ zi,
    const float* __restrict__ V, const float* __restrict__ A,
    float* __restrict__ out)
{
    int n = blockIdx.x * 4 + (threadIdx.x >> 6);
    int lane = threadIdx.x & 63;
    if (n >= N_NODES) return;

    int beg = rowptr[n], end = rowptr[n + 1];
    size_t obase = (size_t)n * DIM + lane;
    if (beg == end) { out[obase] = 0.f; return; }

    float vae = V[0] * A[2 * DIM];
    float sd = s_dst[n];

    float l = 0.f;
    float a0 = 0.f, a1 = 0.f, a2 = 0.f, a3 = 0.f;
    for (int c0 = beg; c0 < end; c0 += 64) {
        int c = c0 + lane;
        bool valid = c < end;
        int2 ed = valid ? edata[c] : make_int2(0, 0);
        int s = ed.x;
        float e = s_src[s] + sd + __int_as_float(ed.y) * vae;
        e = (e >= 0.f) ? e : 0.01f * e;
        float ex = valid ? __expf(e) : 0.f;

        float cs = ex;
        #pragma unroll
        for (int off = 32; off >= 1; off >>= 1) cs += __shfl_xor(cs, off, 64);
        l += cs;

        int cnt = min(64, end - c0);
        int k = 0;
        for (; k + 4 <= cnt; k += 4) {
            int s0 = __shfl(s, k, 64),     s1 = __shfl(s, k + 1, 64),
                s2 = __shfl(s, k + 2, 64), s3 = __shfl(s, k + 3, 64);
            float e0 = __shfl(ex, k, 64),     e1 = __shfl(ex, k + 1, 64),
                  e2 = __shfl(ex, k + 2, 64), e3 = __shfl(ex, k + 3, 64);
            float v0 = bf2f(zb[(size_t)s0 * DIM + lane]);
            float v1 = bf2f(zb[(size_t)s1 * DIM + lane]);
            float v2 = bf2f(zb[(size_t)s2 * DIM + lane]);
            float v3 = bf2f(zb[(size_t)s3 * DIM + lane]);
            a0 += e0 * v0; a1 += e1 * v1; a2 += e2 * v2; a3 += e3 * v3;
        }
        for (; k < cnt; ++k) {
            int sk = __shfl(s, k, 64);
            float ek = __shfl(ex, k, 64);
            a0 += ek * bf2f(zb[(size_t)sk * DIM + lane]);
        }
    }
    float acc = (a0 + a1) + (a2 + a3);
    out[obase] = fmaxf(zi[obase] + acc / l, 0.f);
}

// ============================== driver ==============================
static void run_layer(const float* h, const float* V, const float* W, const float* U, const float* A,
                      const int* rowptr, const int2* edata,
                      ushort* zb, float* zi, float* ssrc, float* sdst,
                      float* out, hipStream_t stream)
{
    node_linear<<<(N_NODES + 63) / 64, 256, 0, stream>>>(h, W, U, A, zb, zi, ssrc, sdst);
    gat_fused<<<(N_NODES + 3) / 4, 256, 0, stream>>>(rowptr, edata, ssrc, sdst, zb, zi, V, A, out);
}

extern "C" void kernel_launch(void* const* d_in, const int* in_sizes, int n_in,
                              void* d_out, int out_size, void* d_ws, size_t ws_size,
                              hipStream_t stream)
{
    const float* h  = (const float*)d_in[0];
    const float* dd = (const float*)d_in[1];
    const int* src  = (const int*)d_in[2];
    const int* dst  = (const int*)d_in[3];
    const float* V0 = (const float*)d_in[4];
    const float* W0 = (const float*)d_in[5];
    const float* U0 = (const float*)d_in[6];
    const float* A0 = (const float*)d_in[7];
    const float* V1 = (const float*)d_in[8];
    const float* W1 = (const float*)d_in[9];
    const float* U1 = (const float*)d_in[10];
    const float* A1 = (const float*)d_in[11];

    const size_t ND = (size_t)N_NODES * DIM;   // 3.2M
    float* ws     = (float*)d_ws;
    ushort* zb    = (ushort*)ws;               // ND ushorts = ND/2 float slots
    float* zi     = ws + ND / 2;               // ND
    float* h1     = zi + ND;                   // ND
    float* ssrc   = h1 + ND;                   // N
    float* sdst   = ssrc + N_NODES;            // N
    int2*  edata  = (int2*)(sdst + N_NODES);   // E int2 (8B-aligned: offset is even #floats)
    int*   counts = (int*)(edata + N_EDGES);   // N
    int*   excl   = counts + N_NODES;          // N
    int*   rowptr = excl + N_NODES;            // N+1
    int*   cursor = rowptr + N_NODES + 1;      // N
    int*   partials = cursor + N_NODES;        // NB_SCAN (<256)
    float* out    = (float*)d_out;

    // ---- CSR build (once; shared by both layers) ----
    hipMemsetAsync(counts, 0, N_NODES * sizeof(int), stream);
    hist_kernel<<<(N_EDGES + 255) / 256, 256, 0, stream>>>(dst, counts);
    scan_blocks<<<NB_SCAN, 256, 0, stream>>>(counts, excl, partials);
    scan_partials<<<1, 256, 0, stream>>>(partials);
    scan_add<<<NB_SCAN, 256, 0, stream>>>(excl, partials, rowptr, cursor);
    scatter_kernel<<<(N_EDGES + 255) / 256, 256, 0, stream>>>(src, dst, dd, cursor, edata);

    // ---- two GAT layers ----
    run_layer(h,  V0, W0, U0, A0, rowptr, edata, zb, zi, ssrc, sdst, h1,  stream);
    run_layer(h1, V1, W1, U1, A1, rowptr, edata, zb, zi, ssrc, sdst, out, stream);
}

// Round 4
// 291.801 us; speedup vs baseline: 2.3877x; 1.0134x over previous
//
#include <hip/hip_runtime.h>
#include <math.h>

#define N_NODES 50000
#define N_EDGES 800000
#define DIM 64
#define NB_SCAN ((N_NODES + 255) / 256)

// ---- bf16 helpers (RNE) ----
__device__ __forceinline__ ushort f2bf(float x) {
    unsigned b = __float_as_uint(x);
    return (ushort)((b + 0x7FFFu + ((b >> 16) & 1u)) >> 16);
}
__device__ __forceinline__ float bf2f(ushort u) {
    return __uint_as_float(((unsigned)u) << 16);
}

// ============================== node GEMM ==============================
// zb = bf16(h @ W^T), zi = h @ U^T, s_src[n] = z[n].A[0:64], s_dst[n] = z[n].A[64:128]
__global__ __launch_bounds__(256) void node_linear(
    const float* __restrict__ h, const float* __restrict__ W,
    const float* __restrict__ U, const float* __restrict__ A,
    ushort* __restrict__ zb, float* __restrict__ zi,
    float* __restrict__ s_src, float* __restrict__ s_dst)
{
    __shared__ float Ws[DIM][DIM + 1];
    __shared__ float Us[DIM][DIM + 1];
    __shared__ float hs[64][DIM + 1];

    const int tid = threadIdx.x;
    const int row0 = blockIdx.x * 64;

    // vectorized staging: 1024 float4 per 64x64 tile
    for (int i = tid; i < 1024; i += 256) {
        int r = i >> 4, c = (i & 15) * 4;
        float4 w4 = ((const float4*)W)[i];
        float4 u4 = ((const float4*)U)[i];
        Ws[r][c] = w4.x; Ws[r][c + 1] = w4.y; Ws[r][c + 2] = w4.z; Ws[r][c + 3] = w4.w;
        Us[r][c] = u4.x; Us[r][c + 1] = u4.y; Us[r][c + 2] = u4.z; Us[r][c + 3] = u4.w;
        int n = row0 + r;
        float4 h4 = (n < N_NODES) ? ((const float4*)h)[((size_t)n * DIM + c) >> 2]
                                  : make_float4(0.f, 0.f, 0.f, 0.f);
        hs[r][c] = h4.x; hs[r][c + 1] = h4.y; hs[r][c + 2] = h4.z; hs[r][c + 3] = h4.w;
    }
    __syncthreads();

    const int rb = (tid >> 4) * 4;
    const int cb = (tid & 15) * 4;

    float accz[4][4] = {{0}}, accu[4][4] = {{0}};
    #pragma unroll 8
    for (int k = 0; k < DIM; ++k) {
        float hv[4], wv[4], uv[4];
        #pragma unroll
        for (int r = 0; r < 4; ++r) hv[r] = hs[rb + r][k];
        #pragma unroll
        for (int c = 0; c < 4; ++c) { wv[c] = Ws[cb + c][k]; uv[c] = Us[cb + c][k]; }
        #pragma unroll
        for (int r = 0; r < 4; ++r)
            #pragma unroll
            for (int c = 0; c < 4; ++c) {
                accz[r][c] += hv[r] * wv[c];
                accu[r][c] += hv[r] * uv[c];
            }
    }

    float asrc[4], adst[4];
    #pragma unroll
    for (int c = 0; c < 4; ++c) { asrc[c] = A[cb + c]; adst[c] = A[DIM + cb + c]; }

    float ps[4], pd[4];
    #pragma unroll
    for (int r = 0; r < 4; ++r) {
        int n = row0 + rb + r;
        if (n < N_NODES) {
            ushort4 vz;
            vz.x = f2bf(accz[r][0]); vz.y = f2bf(accz[r][1]);
            vz.z = f2bf(accz[r][2]); vz.w = f2bf(accz[r][3]);
            *(ushort4*)&zb[(size_t)n * DIM + cb] = vz;
            float4 vu = make_float4(accu[r][0], accu[r][1], accu[r][2], accu[r][3]);
            *(float4*)&zi[(size_t)n * DIM + cb] = vu;
        }
        float s = 0.f, t = 0.f;
        #pragma unroll
        for (int c = 0; c < 4; ++c) { s += accz[r][c] * asrc[c]; t += accz[r][c] * adst[c]; }
        ps[r] = s; pd[r] = t;
    }
    #pragma unroll
    for (int m = 1; m < 16; m <<= 1) {
        #pragma unroll
        for (int r = 0; r < 4; ++r) {
            ps[r] += __shfl_xor(ps[r], m, 64);
            pd[r] += __shfl_xor(pd[r], m, 64);
        }
    }
    if ((tid & 15) == 0) {
        #pragma unroll
        for (int r = 0; r < 4; ++r) {
            int n = row0 + rb + r;
            if (n < N_NODES) { s_src[n] = ps[r]; s_dst[n] = pd[r]; }
        }
    }
}

// ============================== CSR build ==============================
__global__ __launch_bounds__(256) void hist_kernel(const int* __restrict__ dst, int* __restrict__ counts)
{
    int e = blockIdx.x * 256 + threadIdx.x;
    if (e < N_EDGES) atomicAdd(&counts[dst[e]], 1);
}

__global__ __launch_bounds__(256) void scan_blocks(const int* __restrict__ counts,
                                                   int* __restrict__ excl, int* __restrict__ partials)
{
    __shared__ int tmp[256];
    int i = blockIdx.x * 256 + threadIdx.x;
    int v = (i < N_NODES) ? counts[i] : 0;
    tmp[threadIdx.x] = v;
    __syncthreads();
    for (int off = 1; off < 256; off <<= 1) {
        int t = (threadIdx.x >= off) ? tmp[threadIdx.x - off] : 0;
        __syncthreads();
        tmp[threadIdx.x] += t;
        __syncthreads();
    }
    if (i < N_NODES) excl[i] = tmp[threadIdx.x] - v;
    if (threadIdx.x == 255) partials[blockIdx.x] = tmp[255];
}

__global__ __launch_bounds__(256) void scan_partials(int* __restrict__ partials)
{
    __shared__ int tmp[256];
    int v = (threadIdx.x < NB_SCAN) ? partials[threadIdx.x] : 0;
    tmp[threadIdx.x] = v;
    __syncthreads();
    for (int off = 1; off < 256; off <<= 1) {
        int t = (threadIdx.x >= off) ? tmp[threadIdx.x - off] : 0;
        __syncthreads();
        tmp[threadIdx.x] += t;
        __syncthreads();
    }
    if (threadIdx.x < NB_SCAN) partials[threadIdx.x] = tmp[threadIdx.x] - v;
}

__global__ __launch_bounds__(256) void scan_add(const int* __restrict__ excl, const int* __restrict__ partials,
                                                int* __restrict__ rowptr, int* __restrict__ cursor)
{
    int i = blockIdx.x * 256 + threadIdx.x;
    if (i < N_NODES) {
        int v = excl[i] + partials[blockIdx.x];
        rowptr[i] = v;
        cursor[i] = v;
    }
    if (i == 0) rowptr[N_NODES] = N_EDGES;
}

// edata[pos] = (src << 16) | bf16(dval) -- 4 B per edge (src < 50000 < 2^16)
__global__ __launch_bounds__(256) void scatter_kernel(
    const int* __restrict__ src, const int* __restrict__ dst, const float* __restrict__ dfeat,
    int* __restrict__ cursor, unsigned* __restrict__ edata)
{
    int e = blockIdx.x * 256 + threadIdx.x;
    if (e >= N_EDGES) return;
    int t = dst[e];
    int pos = atomicAdd(&cursor[t], 1);
    edata[pos] = ((unsigned)src[e] << 16) | (unsigned)f2bf(dfeat[e]);
}

// ============================== fused GAT ==============================
// one wave per dst node: logits -> softmax (no max-shift; logits are O(1)) ->
// weighted bf16 z-gather with 8-way ILP -> relu(zi + agg/l)
__global__ __launch_bounds__(256) void gat_fused(
    const int* __restrict__ rowptr, const unsigned* __restrict__ edata,
    const float* __restrict__ s_src, const float* __restrict__ s_dst,
    const ushort* __restrict__ zb, const float* __restrict__ zi,
    const float* __restrict__ V, const float* __restrict__ A,
    float* __restrict__ out)
{
    int n = blockIdx.x * 4 + (threadIdx.x >> 6);
    int lane = threadIdx.x & 63;
    if (n >= N_NODES) return;

    int beg = rowptr[n], end = rowptr[n + 1];
    size_t obase = (size_t)n * DIM + lane;
    if (beg == end) { out[obase] = 0.f; return; }

    float vae = V[0] * A[2 * DIM];
    float sd = s_dst[n];

    float l = 0.f;
    float acc[8];
    #pragma unroll
    for (int j = 0; j < 8; ++j) acc[j] = 0.f;

    for (int c0 = beg; c0 < end; c0 += 64) {
        int c = c0 + lane;
        bool valid = c < end;
        unsigned w = valid ? edata[c] : 0u;
        int s = (int)(w >> 16);
        float dv = bf2f((ushort)(w & 0xFFFFu));
        float e = s_src[s] + sd + dv * vae;
        e = (e >= 0.f) ? e : 0.01f * e;
        float ex = valid ? __expf(e) : 0.f;

        float cs = ex;
        #pragma unroll
        for (int off = 32; off >= 1; off >>= 1) cs += __shfl_xor(cs, off, 64);
        l += cs;

        int cnt = min(64, end - c0);
        int k = 0;
        for (; k + 8 <= cnt; k += 8) {
            float vv[8], ee[8];
            #pragma unroll
            for (int j = 0; j < 8; ++j) {
                int sj = __shfl(s, k + j, 64);
                ee[j] = __shfl(ex, k + j, 64);
                vv[j] = bf2f(zb[(size_t)sj * DIM + lane]);
            }
            #pragma unroll
            for (int j = 0; j < 8; ++j) acc[j] += ee[j] * vv[j];
        }
        for (; k < cnt; ++k) {
            int sk = __shfl(s, k, 64);
            float ek = __shfl(ex, k, 64);
            acc[0] += ek * bf2f(zb[(size_t)sk * DIM + lane]);
        }
    }
    float a = ((acc[0] + acc[1]) + (acc[2] + acc[3])) + ((acc[4] + acc[5]) + (acc[6] + acc[7]));
    out[obase] = fmaxf(zi[obase] + a / l, 0.f);
}

// ============================== driver ==============================
static void run_layer(const float* h, const float* V, const float* W, const float* U, const float* A,
                      const int* rowptr, const unsigned* edata,
                      ushort* zb, float* zi, float* ssrc, float* sdst,
                      float* out, hipStream_t stream)
{
    node_linear<<<(N_NODES + 63) / 64, 256, 0, stream>>>(h, W, U, A, zb, zi, ssrc, sdst);
    gat_fused<<<(N_NODES + 3) / 4, 256, 0, stream>>>(rowptr, edata, ssrc, sdst, zb, zi, V, A, out);
}

extern "C" void kernel_launch(void* const* d_in, const int* in_sizes, int n_in,
                              void* d_out, int out_size, void* d_ws, size_t ws_size,
                              hipStream_t stream)
{
    const float* h  = (const float*)d_in[0];
    const float* dd = (const float*)d_in[1];
    const int* src  = (const int*)d_in[2];
    const int* dst  = (const int*)d_in[3];
    const float* V0 = (const float*)d_in[4];
    const float* W0 = (const float*)d_in[5];
    const float* U0 = (const float*)d_in[6];
    const float* A0 = (const float*)d_in[7];
    const float* V1 = (const float*)d_in[8];
    const float* W1 = (const float*)d_in[9];
    const float* U1 = (const float*)d_in[10];
    const float* A1 = (const float*)d_in[11];

    const size_t ND = (size_t)N_NODES * DIM;   // 3.2M
    float* ws     = (float*)d_ws;
    ushort* zb    = (ushort*)ws;               // ND ushorts = ND/2 float slots
    float* zi     = ws + ND / 2;               // ND
    float* h1     = zi + ND;                   // ND
    float* ssrc   = h1 + ND;                   // N
    float* sdst   = ssrc + N_NODES;            // N
    unsigned* edata = (unsigned*)(sdst + N_NODES); // E (4 B per edge)
    int*   counts = (int*)(edata + N_EDGES);   // N
    int*   excl   = counts + N_NODES;          // N
    int*   rowptr = excl + N_NODES;            // N+1
    int*   cursor = rowptr + N_NODES + 1;      // N
    int*   partials = cursor + N_NODES;        // NB_SCAN (<256)
    float* out    = (float*)d_out;

    // ---- CSR build (once; shared by both layers) ----
    hipMemsetAsync(counts, 0, N_NODES * sizeof(int), stream);
    hist_kernel<<<(N_EDGES + 255) / 256, 256, 0, stream>>>(dst, counts);
    scan_blocks<<<NB_SCAN, 256, 0, stream>>>(counts, excl, partials);
    scan_partials<<<1, 256, 0, stream>>>(partials);
    scan_add<<<NB_SCAN, 256, 0, stream>>>(excl, partials, rowptr, cursor);
    scatter_kernel<<<(N_EDGES + 255) / 256, 256, 0, stream>>>(src, dst, dd, cursor, edata);

    // ---- two GAT layers ----
    run_layer(h,  V0, W0, U0, A0, rowptr, edata, zb, zi, ssrc, sdst, h1,  stream);
    run_layer(h1, V1, W1, U1, A1, rowptr, edata, zb, zi, ssrc, sdst, out, stream);
}

// Round 5
// 227.410 us; speedup vs baseline: 3.0638x; 1.2831x over previous
//
#include <hip/hip_runtime.h>
#include <math.h>

#define N_NODES 50000
#define N_EDGES 800000
#define DIM 64
#define NPB 128
#define NPB_SHIFT 7
#define NBUCKET ((N_NODES + NPB - 1) >> NPB_SHIFT)     // 391
#define PART_BLOCKS ((N_EDGES + 4095) / 4096)          // 196

// ---- bf16 helpers (RNE) ----
__device__ __forceinline__ ushort f2bf(float x) {
    unsigned b = __float_as_uint(x);
    return (ushort)((b + 0x7FFFu + ((b >> 16) & 1u)) >> 16);
}
__device__ __forceinline__ float bf2f(ushort u) {
    return __uint_as_float(((unsigned)u) << 16);
}

// ============================== node GEMM ==============================
// zb = bf16(h @ W^T), zi = h @ U^T, s_src[n] = z[n].A[0:64], s_dst[n] = z[n].A[64:128]
__global__ __launch_bounds__(256) void node_linear(
    const float* __restrict__ h, const float* __restrict__ W,
    const float* __restrict__ U, const float* __restrict__ A,
    ushort* __restrict__ zb, float* __restrict__ zi,
    float* __restrict__ s_src, float* __restrict__ s_dst)
{
    __shared__ float Ws[DIM][DIM + 1];
    __shared__ float Us[DIM][DIM + 1];
    __shared__ float hs[64][DIM + 1];

    const int tid = threadIdx.x;
    const int row0 = blockIdx.x * 64;

    for (int i = tid; i < 1024; i += 256) {
        int r = i >> 4, c = (i & 15) * 4;
        float4 w4 = ((const float4*)W)[i];
        float4 u4 = ((const float4*)U)[i];
        Ws[r][c] = w4.x; Ws[r][c + 1] = w4.y; Ws[r][c + 2] = w4.z; Ws[r][c + 3] = w4.w;
        Us[r][c] = u4.x; Us[r][c + 1] = u4.y; Us[r][c + 2] = u4.z; Us[r][c + 3] = u4.w;
        int n = row0 + r;
        float4 h4 = (n < N_NODES) ? ((const float4*)h)[((size_t)n * DIM + c) >> 2]
                                  : make_float4(0.f, 0.f, 0.f, 0.f);
        hs[r][c] = h4.x; hs[r][c + 1] = h4.y; hs[r][c + 2] = h4.z; hs[r][c + 3] = h4.w;
    }
    __syncthreads();

    const int rb = (tid >> 4) * 4;
    const int cb = (tid & 15) * 4;

    float accz[4][4] = {{0}}, accu[4][4] = {{0}};
    #pragma unroll 8
    for (int k = 0; k < DIM; ++k) {
        float hv[4], wv[4], uv[4];
        #pragma unroll
        for (int r = 0; r < 4; ++r) hv[r] = hs[rb + r][k];
        #pragma unroll
        for (int c = 0; c < 4; ++c) { wv[c] = Ws[cb + c][k]; uv[c] = Us[cb + c][k]; }
        #pragma unroll
        for (int r = 0; r < 4; ++r)
            #pragma unroll
            for (int c = 0; c < 4; ++c) {
                accz[r][c] += hv[r] * wv[c];
                accu[r][c] += hv[r] * uv[c];
            }
    }

    float asrc[4], adst[4];
    #pragma unroll
    for (int c = 0; c < 4; ++c) { asrc[c] = A[cb + c]; adst[c] = A[DIM + cb + c]; }

    float ps[4], pd[4];
    #pragma unroll
    for (int r = 0; r < 4; ++r) {
        int n = row0 + rb + r;
        if (n < N_NODES) {
            ushort4 vz;
            vz.x = f2bf(accz[r][0]); vz.y = f2bf(accz[r][1]);
            vz.z = f2bf(accz[r][2]); vz.w = f2bf(accz[r][3]);
            *(ushort4*)&zb[(size_t)n * DIM + cb] = vz;
            float4 vu = make_float4(accu[r][0], accu[r][1], accu[r][2], accu[r][3]);
            *(float4*)&zi[(size_t)n * DIM + cb] = vu;
        }
        float s = 0.f, t = 0.f;
        #pragma unroll
        for (int c = 0; c < 4; ++c) { s += accz[r][c] * asrc[c]; t += accz[r][c] * adst[c]; }
        ps[r] = s; pd[r] = t;
    }
    #pragma unroll
    for (int m = 1; m < 16; m <<= 1) {
        #pragma unroll
        for (int r = 0; r < 4; ++r) {
            ps[r] += __shfl_xor(ps[r], m, 64);
            pd[r] += __shfl_xor(pd[r], m, 64);
        }
    }
    if ((tid & 15) == 0) {
        #pragma unroll
        for (int r = 0; r < 4; ++r) {
            int n = row0 + rb + r;
            if (n < N_NODES) { s_src[n] = ps[r]; s_dst[n] = pd[r]; }
        }
    }
}

// ============================== CSR build (bucketed) ==============================
// Bucket b = dst>>7 (128 nodes per bucket). 4 steps:
// 1) bucket histogram  2) scan bases  3) partition into exclusive bucket ranges
// 4) per-bucket LDS counting sort -> edata (packed) + rowptr

__global__ __launch_bounds__(256) void bucket_hist(const int* __restrict__ dst, int* __restrict__ bhist)
{
    __shared__ int h[NBUCKET];
    for (int b = threadIdx.x; b < NBUCKET; b += 256) h[b] = 0;
    __syncthreads();
    int base = blockIdx.x * 4096;
    #pragma unroll
    for (int j = 0; j < 16; ++j) {
        int e = base + j * 256 + threadIdx.x;
        if (e < N_EDGES) atomicAdd(&h[dst[e] >> NPB_SHIFT], 1);
    }
    __syncthreads();
    for (int b = threadIdx.x; b < NBUCKET; b += 256) {
        int v = h[b];
        if (v) atomicAdd(&bhist[b], v);
    }
}

__global__ __launch_bounds__(512) void bucket_scan(const int* __restrict__ bhist,
                                                   int* __restrict__ bbase, int* __restrict__ gcursor)
{
    __shared__ int tmp[512];
    int t = threadIdx.x;
    int v = (t < NBUCKET) ? bhist[t] : 0;
    tmp[t] = v;
    __syncthreads();
    for (int off = 1; off < 512; off <<= 1) {
        int a = (t >= off) ? tmp[t - off] : 0;
        __syncthreads();
        tmp[t] += a;
        __syncthreads();
    }
    int excl = tmp[t] - v;
    if (t < NBUCKET) { bbase[t] = excl; gcursor[t] = excl; }
    if (t == NBUCKET) bbase[t] = excl;   // == N_EDGES
}

// part[pos] = { (dstLocal<<16)|src , fp32 dval } into bucket-exclusive ranges
__global__ __launch_bounds__(256) void partition_kernel(
    const int* __restrict__ src, const int* __restrict__ dst, const float* __restrict__ dfeat,
    int* __restrict__ gcursor, int2* __restrict__ part)
{
    __shared__ int h[NBUCKET];
    for (int b = threadIdx.x; b < NBUCKET; b += 256) h[b] = 0;
    __syncthreads();
    int base = blockIdx.x * 4096;
    int xw[16]; float yw[16]; int bb[16];
    #pragma unroll
    for (int j = 0; j < 16; ++j) {
        int e = base + j * 256 + threadIdx.x;
        if (e < N_EDGES) {
            int d = dst[e];
            int b = d >> NPB_SHIFT;
            bb[j] = b;
            xw[j] = ((d & (NPB - 1)) << 16) | src[e];
            yw[j] = dfeat[e];
            atomicAdd(&h[b], 1);
        } else bb[j] = -1;
    }
    __syncthreads();
    // reserve: h[b] becomes this block's global write cursor for bucket b
    for (int b = threadIdx.x; b < NBUCKET; b += 256) {
        int v = h[b];
        h[b] = v ? atomicAdd(&gcursor[b], v) : 0;
    }
    __syncthreads();
    #pragma unroll
    for (int j = 0; j < 16; ++j) {
        if (bb[j] >= 0) {
            int pos = atomicAdd(&h[bb[j]], 1);
            part[pos] = make_int2(xw[j], __float_as_int(yw[j]));
        }
    }
}

// one block per bucket: counting sort by local dst; emit edata=(src<<16)|bf16(dval), rowptr
__global__ __launch_bounds__(256) void bucket_sort(
    const int2* __restrict__ part, const int* __restrict__ bbase,
    unsigned* __restrict__ edata, int* __restrict__ rowptr)
{
    __shared__ int cnt[NPB];
    __shared__ int cur[NPB];
    int b = blockIdx.x, t = threadIdx.x;
    int beg = bbase[b], end = bbase[b + 1];
    if (t < NPB) cnt[t] = 0;
    __syncthreads();
    for (int i = beg + t; i < end; i += 256) atomicAdd(&cnt[part[i].x >> 16], 1);
    __syncthreads();
    if (t < NPB) cur[t] = cnt[t];
    __syncthreads();
    for (int off = 1; off < NPB; off <<= 1) {
        int a = (t < NPB && t >= off) ? cur[t - off] : 0;
        __syncthreads();
        if (t < NPB) cur[t] += a;
        __syncthreads();
    }
    int n0 = b << NPB_SHIFT;
    if (t < NPB) {
        int excl = cur[t] - cnt[t];
        int n = n0 + t;
        if (n < N_NODES) rowptr[n] = beg + excl;
        cur[t] = beg + excl;
    }
    if (b == NBUCKET - 1 && t == 0) rowptr[N_NODES] = N_EDGES;
    __syncthreads();
    for (int i = beg + t; i < end; i += 256) {
        int2 ed = part[i];
        int loc = ed.x >> 16;
        int pos = atomicAdd(&cur[loc], 1);
        edata[pos] = ((unsigned)(ed.x & 0xFFFF) << 16) | (unsigned)f2bf(__int_as_float(ed.y));
    }
}

// ============================== fused GAT ==============================
// wave per node; 4 groups x 16 lanes; group g gathers a full 128B z-row (ushort4/lane)
__global__ __launch_bounds__(256) void gat_fused(
    const int* __restrict__ rowptr, const unsigned* __restrict__ edata,
    const float* __restrict__ s_src, const float* __restrict__ s_dst,
    const ushort* __restrict__ zb, const float* __restrict__ zi,
    const float* __restrict__ V, const float* __restrict__ A,
    float* __restrict__ out)
{
    int n = blockIdx.x * 4 + (threadIdx.x >> 6);
    int lane = threadIdx.x & 63;
    int g = lane >> 4, q = lane & 15;
    if (n >= N_NODES) return;

    int beg = rowptr[n], end = rowptr[n + 1];
    if (beg == end) {
        if (lane < 16) ((float4*)out)[(size_t)n * 16 + q] = make_float4(0.f, 0.f, 0.f, 0.f);
        return;
    }

    float vae = V[0] * A[2 * DIM];
    float sd = s_dst[n];

    float l = 0.f;
    float4 a0 = make_float4(0.f, 0.f, 0.f, 0.f);
    float4 a1 = make_float4(0.f, 0.f, 0.f, 0.f);

    for (int c0 = beg; c0 < end; c0 += 64) {
        int c = c0 + lane;
        bool valid = c < end;
        unsigned w = valid ? edata[c] : 0u;
        int s = (int)(w >> 16);
        float dv = bf2f((ushort)(w & 0xFFFFu));
        float e = s_src[s] + sd + dv * vae;
        e = (e >= 0.f) ? e : 0.01f * e;
        float ex = valid ? __expf(e) : 0.f;

        float cs = ex;
        #pragma unroll
        for (int off = 32; off >= 1; off >>= 1) cs += __shfl_xor(cs, off, 64);
        l += cs;

        int cnt = min(64, end - c0);
        for (int k = 0; k < cnt; k += 8) {
            int i0 = k + g, i1 = k + 4 + g;      // always <= 63
            float e0 = __shfl(ex, i0, 64); if (i0 >= cnt) e0 = 0.f;
            float e1 = __shfl(ex, i1, 64); if (i1 >= cnt) e1 = 0.f;
            int s0 = __shfl(s, i0, 64);
            int s1 = __shfl(s, i1, 64);
            ushort4 v0 = *(const ushort4*)&zb[((size_t)s0 << 6) + (q << 2)];
            ushort4 v1 = *(const ushort4*)&zb[((size_t)s1 << 6) + (q << 2)];
            a0.x += e0 * bf2f(v0.x); a0.y += e0 * bf2f(v0.y);
            a0.z += e0 * bf2f(v0.z); a0.w += e0 * bf2f(v0.w);
            a1.x += e1 * bf2f(v1.x); a1.y += e1 * bf2f(v1.y);
            a1.z += e1 * bf2f(v1.z); a1.w += e1 * bf2f(v1.w);
        }
    }
    a0.x += a1.x; a0.y += a1.y; a0.z += a1.z; a0.w += a1.w;
    #pragma unroll
    for (int off = 16; off <= 32; off <<= 1) {
        a0.x += __shfl_xor(a0.x, off, 64);
        a0.y += __shfl_xor(a0.y, off, 64);
        a0.z += __shfl_xor(a0.z, off, 64);
        a0.w += __shfl_xor(a0.w, off, 64);
    }
    if (lane < 16) {
        float inv = 1.f / l;
        float4 z4 = ((const float4*)zi)[(size_t)n * 16 + q];
        float4 o;
        o.x = fmaxf(z4.x + a0.x * inv, 0.f);
        o.y = fmaxf(z4.y + a0.y * inv, 0.f);
        o.z = fmaxf(z4.z + a0.z * inv, 0.f);
        o.w = fmaxf(z4.w + a0.w * inv, 0.f);
        ((float4*)out)[(size_t)n * 16 + q] = o;
    }
}

// ============================== driver ==============================
static void run_layer(const float* h, const float* V, const float* W, const float* U, const float* A,
                      const int* rowptr, const unsigned* edata,
                      ushort* zb, float* zi, float* ssrc, float* sdst,
                      float* out, hipStream_t stream)
{
    node_linear<<<(N_NODES + 63) / 64, 256, 0, stream>>>(h, W, U, A, zb, zi, ssrc, sdst);
    gat_fused<<<(N_NODES + 3) / 4, 256, 0, stream>>>(rowptr, edata, ssrc, sdst, zb, zi, V, A, out);
}

extern "C" void kernel_launch(void* const* d_in, const int* in_sizes, int n_in,
                              void* d_out, int out_size, void* d_ws, size_t ws_size,
                              hipStream_t stream)
{
    const float* h  = (const float*)d_in[0];
    const float* dd = (const float*)d_in[1];
    const int* src  = (const int*)d_in[2];
    const int* dst  = (const int*)d_in[3];
    const float* V0 = (const float*)d_in[4];
    const float* W0 = (const float*)d_in[5];
    const float* U0 = (const float*)d_in[6];
    const float* A0 = (const float*)d_in[7];
    const float* V1 = (const float*)d_in[8];
    const float* W1 = (const float*)d_in[9];
    const float* U1 = (const float*)d_in[10];
    const float* A1 = (const float*)d_in[11];

    const size_t ND = (size_t)N_NODES * DIM;   // 3.2M
    float* ws     = (float*)d_ws;
    ushort* zb    = (ushort*)ws;                   // ND ushort = ND/2 float slots
    float* zi     = ws + ND / 2;                   // ND
    float* h1     = zi + ND;                       // ND
    float* ssrc   = h1 + ND;                       // N
    float* sdst   = ssrc + N_NODES;                // N
    int2*  part   = (int2*)(sdst + N_NODES);       // E int2 (8B aligned: 8.1M floats offset)
    unsigned* edata = (unsigned*)(part + N_EDGES); // E
    int*   bhist  = (int*)(edata + N_EDGES);       // NBUCKET
    int*   bbase  = bhist + NBUCKET;               // NBUCKET+1
    int*   gcursor= bbase + NBUCKET + 1;           // NBUCKET
    int*   rowptr = gcursor + NBUCKET;             // N+1
    float* out    = (float*)d_out;

    // ---- CSR build (once; shared by both layers) ----
    hipMemsetAsync(bhist, 0, NBUCKET * sizeof(int), stream);
    bucket_hist<<<PART_BLOCKS, 256, 0, stream>>>(dst, bhist);
    bucket_scan<<<1, 512, 0, stream>>>(bhist, bbase, gcursor);
    partition_kernel<<<PART_BLOCKS, 256, 0, stream>>>(src, dst, dd, gcursor, part);
    bucket_sort<<<NBUCKET, 256, 0, stream>>>(part, bbase, edata, rowptr);

    // ---- two GAT layers ----
    run_layer(h,  V0, W0, U0, A0, rowptr, edata, zb, zi, ssrc, sdst, h1,  stream);
    run_layer(h1, V1, W1, U1, A1, rowptr, edata, zb, zi, ssrc, sdst, out, stream);
}